// Round 1
// 206.093 us; speedup vs baseline: 1.0461x; 1.0461x over previous
//
#include <hip/hip_runtime.h>

// Fully-fused 4-level Haar DWT for x:(32,3,512,512) f32.
// One workgroup = one (batch, channel, 16-input-row slab).
// Levels: slab 16x512 -> L1 8x256 -> L2 4x128 -> L3 2x64 -> L4 1x32.
// Intermediate LL planes live in LDS (8KB + 2KB + 0.5KB); every subband is
// written to global exactly once, input is read exactly once.
// Level-4 reference quirk (b4 = g4): green (c==1) dups its level-4 stores
// into the blue channel-group slot; blue (c==2) skips level 4.
//
// Out layout (matches harness): t1|t2|t3|t4 concatenated,
// plane index (b*12 + 4*c + s), s in {LL,LH,HL,HH}.

__device__ __forceinline__ void haar2(const float4 r0, const float4 r1,
                                      float2& ll, float2& lh,
                                      float2& hl, float2& hh)
{
    // r0 = input row 2i (4 cols), r1 = input row 2i+1 (same 4 cols)
    float L0 = (r0.x + r1.x) * 0.5f;
    float L1 = (r0.y + r1.y) * 0.5f;
    float L2 = (r0.z + r1.z) * 0.5f;
    float L3 = (r0.w + r1.w) * 0.5f;
    float H0 = fabsf(r0.x - r1.x);
    float H1 = fabsf(r0.y - r1.y);
    float H2 = fabsf(r0.z - r1.z);
    float H3 = fabsf(r0.w - r1.w);
    ll = make_float2((L0 + L1) * 0.5f, (L2 + L3) * 0.5f);
    lh = make_float2(fabsf(L0 - L1), fabsf(L2 - L3));
    hl = make_float2((H0 + H1) * 0.5f, (H2 + H3) * 0.5f);
    hh = make_float2(fabsf(H0 - H1), fabsf(H2 - H3));
}

__global__ __launch_bounds__(256) void dwt_fused(
    const float* __restrict__ src, float* __restrict__ out)
{
    __shared__ float ll1[8][256];   // level-1 LL slab
    __shared__ float ll2[4][128];   // level-2 LL slab
    __shared__ float ll3[2][64];    // level-3 LL slab

    const int slab  = blockIdx.x;   // 0..31 (16 input rows each)
    const int plane = blockIdx.y;   // 0..95
    const int b = plane / 3;
    const int c = plane - 3 * b;
    const int tid = threadIdx.x;

    const long t2_off = 32L * 12 * 256 * 256;
    const long t3_off = t2_off + 32L * 12 * 128 * 128;
    const long t4_off = t3_off + 32L * 12 * 64 * 64;

    const float* sp = src + (long)plane * (512L * 512)
                          + (long)slab * 16 * 512;

    // ---- Level 1: 8 out rows x 256 cols (1024 col-pair items, 4 per thread)
    {
        const long hw = 256L * 256;
        float* dp_base = out + (long)(b * 12 + 4 * c) * hw;
        #pragma unroll
        for (int k = 0; k < 4; ++k) {
            int pid = k * 256 + tid;      // 0..1023
            int i   = pid >> 7;           // local out row 0..7
            int jw  = pid & 127;          // col-pair 0..127
            const float4 r0 = *((const float4*)(sp + (long)(2 * i)     * 512) + jw);
            const float4 r1 = *((const float4*)(sp + (long)(2 * i + 1) * 512) + jw);
            float2 ll, lh, hl, hh;
            haar2(r0, r1, ll, lh, hl, hh);
            float* dp = dp_base + (long)(slab * 8 + i) * 256 + 2 * jw;
            *(float2*)(dp + 0 * hw) = ll;
            *(float2*)(dp + 1 * hw) = lh;
            *(float2*)(dp + 2 * hw) = hl;
            *(float2*)(dp + 3 * hw) = hh;
            *(float2*)&ll1[i][2 * jw] = ll;
        }
    }
    __syncthreads();

    // ---- Level 2: 4 out rows x 128 cols (512 px, 2 px/thread, all 256 threads)
    {
        int i  = tid >> 6;               // 0..3
        int jw = tid & 63;               // 0..63
        const float4 r0 = *((const float4*)&ll1[2 * i][4 * jw]);
        const float4 r1 = *((const float4*)&ll1[2 * i + 1][4 * jw]);
        float2 ll, lh, hl, hh;
        haar2(r0, r1, ll, lh, hl, hh);
        const long hw = 128L * 128;
        float* dp = out + t2_off + (long)(b * 12 + 4 * c) * hw
                        + (long)(slab * 4 + i) * 128 + 2 * jw;
        *(float2*)(dp + 0 * hw) = ll;
        *(float2*)(dp + 1 * hw) = lh;
        *(float2*)(dp + 2 * hw) = hl;
        *(float2*)(dp + 3 * hw) = hh;
        *(float2*)&ll2[i][2 * jw] = ll;
    }
    __syncthreads();

    // ---- Level 3: 2 out rows x 64 cols (128 px, first 64 threads)
    if (tid < 64) {
        int i  = tid >> 5;               // 0..1
        int jw = tid & 31;               // 0..31
        const float4 r0 = *((const float4*)&ll2[2 * i][4 * jw]);
        const float4 r1 = *((const float4*)&ll2[2 * i + 1][4 * jw]);
        float2 ll, lh, hl, hh;
        haar2(r0, r1, ll, lh, hl, hh);
        const long hw = 64L * 64;
        float* dp = out + t3_off + (long)(b * 12 + 4 * c) * hw
                        + (long)(slab * 2 + i) * 64 + 2 * jw;
        *(float2*)(dp + 0 * hw) = ll;
        *(float2*)(dp + 1 * hw) = lh;
        *(float2*)(dp + 2 * hw) = hl;
        *(float2*)(dp + 3 * hw) = hh;
        *(float2*)&ll3[i][2 * jw] = ll;
    }
    __syncthreads();

    // ---- Level 4: 1 out row x 32 cols (32 px, first 16 threads).
    // Reference bug preserved: b4 = g4 -> c==1 dups, c==2 skips.
    if (c < 2 && tid < 16) {
        int jw = tid;                    // 0..15
        const float4 r0 = *((const float4*)&ll3[0][4 * jw]);
        const float4 r1 = *((const float4*)&ll3[1][4 * jw]);
        float2 ll, lh, hl, hh;
        haar2(r0, r1, ll, lh, hl, hh);
        const long hw = 32L * 32;
        float* dp = out + t4_off + (long)(b * 12 + 4 * c) * hw
                        + (long)slab * 32 + 2 * jw;
        *(float2*)(dp + 0 * hw) = ll;
        *(float2*)(dp + 1 * hw) = lh;
        *(float2*)(dp + 2 * hw) = hl;
        *(float2*)(dp + 3 * hw) = hh;
        if (c == 1) {                    // duplicate green level-4 into blue slot
            float* dp2 = dp + 4 * hw;
            *(float2*)(dp2 + 0 * hw) = ll;
            *(float2*)(dp2 + 1 * hw) = lh;
            *(float2*)(dp2 + 2 * hw) = hl;
            *(float2*)(dp2 + 3 * hw) = hh;
        }
    }
}

extern "C" void kernel_launch(void* const* d_in, const int* in_sizes, int n_in,
                              void* d_out, int out_size, void* d_ws, size_t ws_size,
                              hipStream_t stream) {
    const float* x = (const float*)d_in[0];
    float* out = (float*)d_out;
    // grid: 32 slabs x 96 (b,c) planes; 256 threads; ~10.75 KB LDS
    dwt_fused<<<dim3(32, 96), dim3(256), 0, stream>>>(x, out);
}